// Round 1
// baseline (9229.933 us; speedup 1.0000x reference)
//
#include <hip/hip_runtime.h>

#define D 128
#define RNUM 7
#define GNUM 64
#define LAYERS 3
#define BM 64

// x0[n,:] = emb[unit_type[n],:]   (float4 per thread, 32 threads/node)
__global__ __launch_bounds__(256) void init_x_kernel(const int* __restrict__ ut,
    const float* __restrict__ emb, float* __restrict__ x, int n) {
  int tid = blockIdx.x * 256 + threadIdx.x;
  int nidx = tid >> 5, q = tid & 31;
  if (nidx >= n) return;
  ((float4*)x)[nidx * 32 + q] = ((const float4*)emb)[ut[nidx] * 32 + q];
}

// C[n,d] = (bias0?bias0[d]:0) + (bias1?bias1[d]:0) + sum_k A[n,k]*B[k,d]
// A: nrows x 128, B: 128 x 128. Block: 64 rows x 128 cols, 256 threads,
// each thread 8 rows x 4 cols (float4 col group).
__global__ __launch_bounds__(256) void gemm128_kernel(const float* __restrict__ A,
    const float* __restrict__ B, const float* __restrict__ bias0,
    const float* __restrict__ bias1, float* __restrict__ C, int nrows) {
  __shared__ float As[BM * D];
  const int t = threadIdx.x;
  const int row0 = blockIdx.x * BM;

  // stage A tile (64x128 fp32 = 8192 floats = 2048 float4), coalesced
#pragma unroll
  for (int j = 0; j < 8; ++j) {
    int idx = t + j * 256;          // float4 index in tile
    int r = idx >> 5, c = idx & 31; // 32 float4 per row
    int grow = row0 + r;
    float4 v = make_float4(0.f, 0.f, 0.f, 0.f);
    if (grow < nrows) v = ((const float4*)A)[(size_t)grow * 32 + c];
    ((float4*)As)[idx] = v;
  }
  __syncthreads();

  const int tc = t & 31;  // col group: cols tc*4 .. tc*4+3
  const int tr = t >> 5;  // row group: rows tr*8 .. tr*8+7

  float acc[8][4];
#pragma unroll
  for (int i = 0; i < 8; ++i)
#pragma unroll
    for (int j = 0; j < 4; ++j) acc[i][j] = 0.f;

  const float4* B4 = (const float4*)B;
  for (int k = 0; k < D; k += 4) {
    float4 a[8];
#pragma unroll
    for (int i = 0; i < 8; ++i)
      a[i] = *(const float4*)&As[(tr * 8 + i) * D + k];
#pragma unroll
    for (int kk = 0; kk < 4; ++kk) {
      float4 w = B4[(k + kk) * 32 + tc];
#pragma unroll
      for (int i = 0; i < 8; ++i) {
        float av = (kk == 0) ? a[i].x : (kk == 1) ? a[i].y : (kk == 2) ? a[i].z : a[i].w;
        acc[i][0] += av * w.x;
        acc[i][1] += av * w.y;
        acc[i][2] += av * w.z;
        acc[i][3] += av * w.w;
      }
    }
  }

  float b0 = 0.f, b1 = 0.f, b2 = 0.f, b3 = 0.f;
  if (bias0) {
    b0 += bias0[tc * 4 + 0]; b1 += bias0[tc * 4 + 1];
    b2 += bias0[tc * 4 + 2]; b3 += bias0[tc * 4 + 3];
  }
  if (bias1) {
    b0 += bias1[tc * 4 + 0]; b1 += bias1[tc * 4 + 1];
    b2 += bias1[tc * 4 + 2]; b3 += bias1[tc * 4 + 3];
  }
#pragma unroll
  for (int i = 0; i < 8; ++i) {
    int grow = row0 + tr * 8 + i;
    if (grow < nrows) {
      float4 o = make_float4(acc[i][0] + b0, acc[i][1] + b1,
                             acc[i][2] + b2, acc[i][3] + b3);
      ((float4*)C)[(size_t)grow * 32 + tc] = o;
    }
  }
}

// For edges with relation==rsel: h[out,:] += ew * y[in,:]
// 32 threads per edge, float4 gather + 4 scalar atomics each.
__global__ __launch_bounds__(256) void scatter_kernel(const int* __restrict__ nin,
    const int* __restrict__ nout, const int* __restrict__ rel,
    const float* __restrict__ ew, const float* __restrict__ y,
    float* __restrict__ h, int rsel, int ne) {
  int tid = blockIdx.x * 256 + threadIdx.x;
  int e = tid >> 5, q = tid & 31;
  if (e >= ne) return;
  if (rel[e] != rsel) return;
  float w = ew[e];
  float4 v = ((const float4*)y)[(size_t)nin[e] * 32 + q];
  float* dst = h + (size_t)nout[e] * D + q * 4;
  atomicAdd(dst + 0, v.x * w);
  atomicAdd(dst + 1, v.y * w);
  atomicAdd(dst + 2, v.z * w);
  atomicAdd(dst + 3, v.w * w);
}

__global__ __launch_bounds__(256) void relu_kernel(float* __restrict__ x, int n4) {
  int tid = blockIdx.x * 256 + threadIdx.x;
  if (tid >= n4) return;
  float4 v = ((float4*)x)[tid];
  v.x = fmaxf(v.x, 0.f);
  v.y = fmaxf(v.y, 0.f);
  v.z = fmaxf(v.z, 0.f);
  v.w = fmaxf(v.w, 0.f);
  ((float4*)x)[tid] = v;
}

// node2graph is sorted: accumulate in register, flush atomic only at graph
// boundary. Block covers 256 nodes: 2 sub-chunks x 128 d-lanes.
__global__ __launch_bounds__(256) void pool_kernel(const float* __restrict__ x,
    const int* __restrict__ n2g, float* __restrict__ gf, int n) {
  int d = threadIdx.x & 127;
  int sub = threadIdx.x >> 7;
  int n0 = (blockIdx.x * 2 + sub) * 128;
  int nend = n0 + 128;
  if (nend > n) nend = n;
  float acc = 0.f;
  int gcur = -1;
  for (int i = n0; i < nend; ++i) {
    int g = n2g[i];
    if (g != gcur) {
      if (gcur >= 0) atomicAdd(&gf[gcur * D + d], acc);
      gcur = g;
      acc = 0.f;
    }
    acc += x[(size_t)i * D + d];
  }
  if (gcur >= 0) atomicAdd(&gf[gcur * D + d], acc);
}

extern "C" void kernel_launch(void* const* d_in, const int* in_sizes, int n_in,
                              void* d_out, int out_size, void* d_ws, size_t ws_size,
                              hipStream_t stream) {
  const int*   unit_type  = (const int*)d_in[0];
  const int*   node_in    = (const int*)d_in[1];
  const int*   node_out   = (const int*)d_in[2];
  const int*   relation   = (const int*)d_in[3];
  const float* edge_w     = (const float*)d_in[4];
  const int*   node2graph = (const int*)d_in[5];
  const float* emb        = (const float*)d_in[6];
  const float* W_rel      = (const float*)d_in[7];
  const float* b_rel      = (const float*)d_in[8];
  const float* W_loop     = (const float*)d_in[9];
  const float* b_loop     = (const float*)d_in[10];

  const int n  = in_sizes[0];
  const int ne = in_sizes[1];
  float* out = (float*)d_out;

  const size_t ND = (size_t)n * D;
  float* x0 = (float*)d_ws;
  float* x1 = x0 + ND;
  float* y  = x1 + ND;

  // zero graph_feature region of output (atomics accumulate into it)
  hipMemsetAsync(d_out, 0, (size_t)GNUM * D * sizeof(float), stream);

  const int nq = n * 32;  // float4 count for an N x D buffer
  init_x_kernel<<<(nq + 255) / 256, 256, 0, stream>>>(unit_type, emb, x0, n);

  const int gemm_blocks = (n + BM - 1) / BM;
  const int scat_blocks = (ne * 32 + 255) / 256;

  float* cur = x0;
  for (int i = 0; i < LAYERS; ++i) {
    float* nxt = (i == LAYERS - 1) ? (out + GNUM * D) : (cur == x0 ? x1 : x0);
    // next = b_rel[i] + b_loop[i] + cur @ W_loop[i]   (initializes next)
    gemm128_kernel<<<gemm_blocks, 256, 0, stream>>>(
        cur, W_loop + (size_t)i * D * D, b_rel + (size_t)i * D,
        b_loop + (size_t)i * D, nxt, n);
    for (int r = 0; r < RNUM; ++r) {
      // y = cur @ W_rel[i][r*D:(r+1)*D, :]
      gemm128_kernel<<<gemm_blocks, 256, 0, stream>>>(
          cur, W_rel + (size_t)i * RNUM * D * D + (size_t)r * D * D,
          nullptr, nullptr, y, n);
      // next[out] += ew * y[in] for edges with relation == r
      scatter_kernel<<<scat_blocks, 256, 0, stream>>>(
          node_in, node_out, relation, edge_w, y, nxt, r, ne);
    }
    relu_kernel<<<(nq + 255) / 256, 256, 0, stream>>>(nxt, nq);
    cur = nxt;
  }

  pool_kernel<<<(n + 255) / 256, 256, 0, stream>>>(cur, node2graph, out, n);
}

// Round 2
// 2229.233 us; speedup vs baseline: 4.1404x; 4.1404x over previous
//
#include <hip/hip_runtime.h>

#define D 128
#define RNUM 7
#define GNUM 64
#define LAYERS 3
#define MBLK 16   // dest nodes per block in layer kernel

// ---------- x0[n,:] = emb[unit_type[n],:] ----------
__global__ __launch_bounds__(256) void init_x_kernel(const int* __restrict__ ut,
    const float* __restrict__ emb, float* __restrict__ x, int n) {
  int tid = blockIdx.x * 256 + threadIdx.x;
  int nidx = tid >> 5, q = tid & 31;
  if (nidx >= n) return;
  ((float4*)x)[(size_t)nidx * 32 + q] = ((const float4*)emb)[(size_t)ut[nidx] * 32 + q];
}

// ---------- CSR build: histogram over dest node ----------
__global__ __launch_bounds__(256) void hist_kernel(const int* __restrict__ nout,
    int* __restrict__ hist, int ne) {
  int e = blockIdx.x * 256 + threadIdx.x;
  if (e >= ne) return;
  atomicAdd(&hist[nout[e]], 1);
}

// ---------- exclusive scan of hist -> row_ptr, cursor (single block) ----------
__global__ __launch_bounds__(256) void scan_kernel(const int* __restrict__ hist,
    int* __restrict__ row_ptr, int* __restrict__ cursor, int n) {
  __shared__ int buf[256];
  __shared__ int carry_s;
  const int t = threadIdx.x;
  if (t == 0) carry_s = 0;
  __syncthreads();
  const int nch = (n + 1023) / 1024;
  for (int c = 0; c < nch; ++c) {
    int base = c * 1024 + t * 4;
    int v0 = 0, v1 = 0, v2 = 0, v3 = 0;
    if (base + 3 < n) {
      int4 h4 = *(const int4*)&hist[base];
      v0 = h4.x; v1 = h4.y; v2 = h4.z; v3 = h4.w;
    } else {
      if (base + 0 < n) v0 = hist[base + 0];
      if (base + 1 < n) v1 = hist[base + 1];
      if (base + 2 < n) v2 = hist[base + 2];
      if (base + 3 < n) v3 = hist[base + 3];
    }
    int tsum = v0 + v1 + v2 + v3;
    buf[t] = tsum;
    __syncthreads();
    for (int off = 1; off < 256; off <<= 1) {
      int add = (t >= off) ? buf[t - off] : 0;
      __syncthreads();
      buf[t] += add;
      __syncthreads();
    }
    int incl = buf[t];
    int e0 = incl - tsum + carry_s;   // exclusive start for this thread's 4 bins
    int e1 = e0 + v0, e2 = e1 + v1, e3 = e2 + v2;
    if (base + 0 < n) { row_ptr[base + 0] = e0; cursor[base + 0] = e0; }
    if (base + 1 < n) { row_ptr[base + 1] = e1; cursor[base + 1] = e1; }
    if (base + 2 < n) { row_ptr[base + 2] = e2; cursor[base + 2] = e2; }
    if (base + 3 < n) { row_ptr[base + 3] = e3; cursor[base + 3] = e3; }
    __syncthreads();                  // everyone has read carry_s
    if (t == 255) carry_s += incl;
    __syncthreads();
  }
  if (t == 0) row_ptr[n] = carry_s;
}

// ---------- fill CSR edge records: (node_in | rel<<16, ew) ----------
__global__ __launch_bounds__(256) void fill_kernel(const int* __restrict__ nin,
    const int* __restrict__ nout, const int* __restrict__ rel,
    const float* __restrict__ ew, int* __restrict__ cursor,
    int2* __restrict__ erec, int ne) {
  int e = blockIdx.x * 256 + threadIdx.x;
  if (e >= ne) return;
  int pos = atomicAdd(&cursor[nout[e]], 1);
  erec[pos] = make_int2(nin[e] | (rel[e] << 16), __float_as_int(ew[e]));
}

// ---------- fused layer: CSR-gather upd tile in LDS, then transform ----------
// h[m,:] = relu( upd(16x896)@Wrel + x[m,:]@Wloop + brel + bloop )
__global__ __launch_bounds__(256) void layer_kernel(
    const float* __restrict__ x, const int2* __restrict__ erec,
    const int* __restrict__ row_ptr,
    const float* __restrict__ Wrel, const float* __restrict__ brel,
    const float* __restrict__ Wloop, const float* __restrict__ bloop,
    float* __restrict__ h, int n) {
  __shared__ float upd[MBLK][RNUM * D];   // 16 x 896 fp32 = 56 KB
  const int t = threadIdx.x;
  const int m0 = blockIdx.x * MBLK;
  const float4* X4 = (const float4*)x;

  // zero the tile: 16*896/4 = 3584 float4
  for (int j = t; j < MBLK * RNUM * D / 4; j += 256)
    ((float4*)upd)[j] = make_float4(0.f, 0.f, 0.f, 0.f);
  __syncthreads();

  // aggregation: 8 half-waves, each owns 2 dest rows (no LDS write races)
  {
    const int hw = t >> 5;        // half-wave id 0..7
    const int lane = t & 31;      // float4 lane within the 128-float row
    for (int mi = 0; mi < 2; ++mi) {
      const int m = hw * 2 + mi;
      const int node = m0 + m;
      if (node < n) {
        int s = row_ptr[node], e = row_ptr[node + 1];
        int j = s;
        for (; j + 1 < e; j += 2) {
          int2 r0 = erec[j];
          int2 r1 = erec[j + 1];
          float4 v0 = X4[(size_t)(r0.x & 0xffff) * 32 + lane];
          float4 v1 = X4[(size_t)(r1.x & 0xffff) * 32 + lane];
          float w0 = __int_as_float(r0.y);
          float w1 = __int_as_float(r1.y);
          float* d0 = &upd[m][(r0.x >> 16) * D + lane * 4];
          float4 c0 = *(float4*)d0;
          c0.x += w0 * v0.x; c0.y += w0 * v0.y;
          c0.z += w0 * v0.z; c0.w += w0 * v0.w;
          *(float4*)d0 = c0;
          float* d1 = &upd[m][(r1.x >> 16) * D + lane * 4];
          float4 c1 = *(float4*)d1;
          c1.x += w1 * v1.x; c1.y += w1 * v1.y;
          c1.z += w1 * v1.z; c1.w += w1 * v1.w;
          *(float4*)d1 = c1;
        }
        if (j < e) {
          int2 r0 = erec[j];
          float4 v0 = X4[(size_t)(r0.x & 0xffff) * 32 + lane];
          float w0 = __int_as_float(r0.y);
          float* d0 = &upd[m][(r0.x >> 16) * D + lane * 4];
          float4 c0 = *(float4*)d0;
          c0.x += w0 * v0.x; c0.y += w0 * v0.y;
          c0.z += w0 * v0.z; c0.w += w0 * v0.w;
          *(float4*)d0 = c0;
        }
      }
    }
  }
  __syncthreads();

  // transform: thread -> 2 rows (tr), 4 cols (tc as float4)
  const int tc = t & 31;
  const int tr = t >> 5;          // 0..7
  const int r0 = tr * 2, r1 = r0 + 1;
  const int g0 = m0 + r0, g1 = m0 + r1;
  float4 acc0 = make_float4(0.f, 0.f, 0.f, 0.f);
  float4 acc1 = make_float4(0.f, 0.f, 0.f, 0.f);

  const float4* Wr4 = (const float4*)Wrel;    // 896 x 32 float4
  for (int k = 0; k < RNUM * D; k += 4) {
    float4 a0 = *(const float4*)&upd[r0][k];
    float4 a1 = *(const float4*)&upd[r1][k];
#pragma unroll
    for (int kk = 0; kk < 4; ++kk) {
      float4 w = Wr4[(size_t)(k + kk) * 32 + tc];
      float e0 = (kk == 0) ? a0.x : (kk == 1) ? a0.y : (kk == 2) ? a0.z : a0.w;
      float e1 = (kk == 0) ? a1.x : (kk == 1) ? a1.y : (kk == 2) ? a1.z : a1.w;
      acc0.x += e0 * w.x; acc0.y += e0 * w.y; acc0.z += e0 * w.z; acc0.w += e0 * w.w;
      acc1.x += e1 * w.x; acc1.y += e1 * w.y; acc1.z += e1 * w.z; acc1.w += e1 * w.w;
    }
  }
  // self-loop term: x rows straight from global (L2-warm from phase A)
  const float4* Wl4 = (const float4*)Wloop;   // 128 x 32 float4
  const bool ok0 = g0 < n, ok1 = g1 < n;
  for (int k = 0; k < D; k += 4) {
    float4 a0 = ok0 ? X4[(size_t)g0 * 32 + (k >> 2)] : make_float4(0, 0, 0, 0);
    float4 a1 = ok1 ? X4[(size_t)g1 * 32 + (k >> 2)] : make_float4(0, 0, 0, 0);
#pragma unroll
    for (int kk = 0; kk < 4; ++kk) {
      float4 w = Wl4[(size_t)(k + kk) * 32 + tc];
      float e0 = (kk == 0) ? a0.x : (kk == 1) ? a0.y : (kk == 2) ? a0.z : a0.w;
      float e1 = (kk == 0) ? a1.x : (kk == 1) ? a1.y : (kk == 2) ? a1.z : a1.w;
      acc0.x += e0 * w.x; acc0.y += e0 * w.y; acc0.z += e0 * w.z; acc0.w += e0 * w.w;
      acc1.x += e1 * w.x; acc1.y += e1 * w.y; acc1.z += e1 * w.z; acc1.w += e1 * w.w;
    }
  }

  float4 br = ((const float4*)brel)[tc];
  float4 bl = ((const float4*)bloop)[tc];
  float4 bias = make_float4(br.x + bl.x, br.y + bl.y, br.z + bl.z, br.w + bl.w);

  if (ok0) {
    float4 o;
    o.x = fmaxf(acc0.x + bias.x, 0.f); o.y = fmaxf(acc0.y + bias.y, 0.f);
    o.z = fmaxf(acc0.z + bias.z, 0.f); o.w = fmaxf(acc0.w + bias.w, 0.f);
    ((float4*)h)[(size_t)g0 * 32 + tc] = o;
  }
  if (ok1) {
    float4 o;
    o.x = fmaxf(acc1.x + bias.x, 0.f); o.y = fmaxf(acc1.y + bias.y, 0.f);
    o.z = fmaxf(acc1.z + bias.z, 0.f); o.w = fmaxf(acc1.w + bias.w, 0.f);
    ((float4*)h)[(size_t)g1 * 32 + tc] = o;
  }
}

// ---------- graph pooling (node2graph sorted) ----------
__global__ __launch_bounds__(256) void pool_kernel(const float* __restrict__ x,
    const int* __restrict__ n2g, float* __restrict__ gf, int n) {
  int d = threadIdx.x & 127;
  int sub = threadIdx.x >> 7;
  int n0 = (blockIdx.x * 2 + sub) * 128;
  int nend = n0 + 128;
  if (nend > n) nend = n;
  float acc = 0.f;
  int gcur = -1;
  for (int i = n0; i < nend; ++i) {
    int g = n2g[i];
    if (g != gcur) {
      if (gcur >= 0) atomicAdd(&gf[gcur * D + d], acc);
      gcur = g;
      acc = 0.f;
    }
    acc += x[(size_t)i * D + d];
  }
  if (gcur >= 0) atomicAdd(&gf[gcur * D + d], acc);
}

extern "C" void kernel_launch(void* const* d_in, const int* in_sizes, int n_in,
                              void* d_out, int out_size, void* d_ws, size_t ws_size,
                              hipStream_t stream) {
  const int*   unit_type  = (const int*)d_in[0];
  const int*   node_in    = (const int*)d_in[1];
  const int*   node_out   = (const int*)d_in[2];
  const int*   relation   = (const int*)d_in[3];
  const float* edge_w     = (const float*)d_in[4];
  const int*   node2graph = (const int*)d_in[5];
  const float* emb        = (const float*)d_in[6];
  const float* W_rel      = (const float*)d_in[7];
  const float* b_rel      = (const float*)d_in[8];
  const float* W_loop     = (const float*)d_in[9];
  const float* b_loop     = (const float*)d_in[10];

  const int n  = in_sizes[0];
  const int ne = in_sizes[1];
  float* out = (float*)d_out;

  // workspace layout
  const size_t ND = (size_t)n * D;
  float* x0      = (float*)d_ws;
  float* x1      = x0 + ND;
  int2*  erec    = (int2*)(x1 + ND);
  int*   hist    = (int*)(erec + ne);
  int*   row_ptr = hist + n;
  int*   cursor  = row_ptr + ((n + 4) & ~3);   // keep 16B alignment

  // zero graph_feature region + histogram
  hipMemsetAsync(d_out, 0, (size_t)GNUM * D * sizeof(float), stream);
  hipMemsetAsync(hist, 0, (size_t)n * sizeof(int), stream);

  const int eblocks = (ne + 255) / 256;
  hist_kernel<<<eblocks, 256, 0, stream>>>(node_out, hist, ne);
  scan_kernel<<<1, 256, 0, stream>>>(hist, row_ptr, cursor, n);
  fill_kernel<<<eblocks, 256, 0, stream>>>(node_in, node_out, relation, edge_w,
                                           cursor, erec, ne);

  const int nq = n * 32;
  init_x_kernel<<<(nq + 255) / 256, 256, 0, stream>>>(unit_type, emb, x0, n);

  const int lblocks = (n + MBLK - 1) / MBLK;
  float* cur = x0;
  for (int i = 0; i < LAYERS; ++i) {
    float* nxt = (i == LAYERS - 1) ? (out + GNUM * D) : (cur == x0 ? x1 : x0);
    layer_kernel<<<lblocks, 256, 0, stream>>>(
        cur, erec, row_ptr,
        W_rel + (size_t)i * RNUM * D * D, b_rel + (size_t)i * D,
        W_loop + (size_t)i * D * D, b_loop + (size_t)i * D,
        nxt, n);
    cur = nxt;
  }

  pool_kernel<<<(n + 255) / 256, 256, 0, stream>>>(cur, node2graph, out, n);
}

// Round 3
// 1774.806 us; speedup vs baseline: 5.2005x; 1.2560x over previous
//
#include <hip/hip_runtime.h>

#define D 128
#define RNUM 7
#define GNUM 64
#define LAYERS 3
#define MBLK 16          // dest nodes per block in layer kernel
#define SEG_SHIFT 3      // segments = node*8 + rel (slot 7 empty)

// ---------- x0[n,:] = emb[unit_type[n],:] ----------
__global__ __launch_bounds__(256) void init_x_kernel(const int* __restrict__ ut,
    const float* __restrict__ emb, float* __restrict__ x, int n) {
  int tid = blockIdx.x * 256 + threadIdx.x;
  int nidx = tid >> 5, q = tid & 31;
  if (nidx >= n) return;
  ((float4*)x)[(size_t)nidx * 32 + q] = ((const float4*)emb)[(size_t)ut[nidx] * 32 + q];
}

// ---------- CSR build: histogram over (dest node, rel) segments ----------
__global__ __launch_bounds__(256) void hist_kernel(const int* __restrict__ nout,
    const int* __restrict__ rel, int* __restrict__ hist, int ne) {
  int e = blockIdx.x * 256 + threadIdx.x;
  if (e >= ne) return;
  atomicAdd(&hist[(nout[e] << SEG_SHIFT) | rel[e]], 1);
}

// ---------- scan stage 1: per-block (1024 elems) exclusive scan + totals ----------
__global__ __launch_bounds__(256) void scan1_kernel(const int* __restrict__ hist,
    int* __restrict__ row_ptr, int* __restrict__ partials, int nseg) {
  __shared__ int buf[256];
  const int t = threadIdx.x;
  const int base = blockIdx.x * 1024 + t * 4;
  int v0 = 0, v1 = 0, v2 = 0, v3 = 0;
  if (base + 3 < nseg) {
    int4 h4 = *(const int4*)&hist[base];
    v0 = h4.x; v1 = h4.y; v2 = h4.z; v3 = h4.w;
  } else {
    if (base + 0 < nseg) v0 = hist[base + 0];
    if (base + 1 < nseg) v1 = hist[base + 1];
    if (base + 2 < nseg) v2 = hist[base + 2];
    if (base + 3 < nseg) v3 = hist[base + 3];
  }
  int tsum = v0 + v1 + v2 + v3;
  buf[t] = tsum;
  __syncthreads();
  for (int off = 1; off < 256; off <<= 1) {
    int add = (t >= off) ? buf[t - off] : 0;
    __syncthreads();
    buf[t] += add;
    __syncthreads();
  }
  int incl = buf[t];
  int e0 = incl - tsum;   // block-local exclusive
  int e1 = e0 + v0, e2 = e1 + v1, e3 = e2 + v2;
  if (base + 0 < nseg) row_ptr[base + 0] = e0;
  if (base + 1 < nseg) row_ptr[base + 1] = e1;
  if (base + 2 < nseg) row_ptr[base + 2] = e2;
  if (base + 3 < nseg) row_ptr[base + 3] = e3;
  if (t == 255) partials[blockIdx.x] = incl;
}

// ---------- scan stage 2: exclusive scan of block totals (single block) ----------
__global__ __launch_bounds__(256) void scan2_kernel(int* __restrict__ partials, int nb) {
  __shared__ int buf[256];
  __shared__ int carry_s;
  const int t = threadIdx.x;
  if (t == 0) carry_s = 0;
  __syncthreads();
  for (int c0 = 0; c0 < nb; c0 += 256) {
    int i = c0 + t;
    int v = (i < nb) ? partials[i] : 0;
    buf[t] = v;
    __syncthreads();
    for (int off = 1; off < 256; off <<= 1) {
      int add = (t >= off) ? buf[t - off] : 0;
      __syncthreads();
      buf[t] += add;
      __syncthreads();
    }
    int incl = buf[t];
    int excl = incl - v + carry_s;
    if (i < nb) partials[i] = excl;
    __syncthreads();              // everyone has read carry_s
    if (t == 255) carry_s += incl;
    __syncthreads();
  }
}

// ---------- scan stage 3: add block offsets, init cursor ----------
__global__ __launch_bounds__(256) void scan3_kernel(int* __restrict__ row_ptr,
    int* __restrict__ cursor, const int* __restrict__ partials, int nseg, int ne) {
  int i = blockIdx.x * 256 + threadIdx.x;
  if (i < nseg) {
    int v = row_ptr[i] + partials[i >> 10];
    row_ptr[i] = v;
    cursor[i] = v;
  }
  if (i == 0) row_ptr[nseg] = ne;
}

// ---------- fill CSR edge records: (node_in, ew) ----------
__global__ __launch_bounds__(256) void fill_kernel(const int* __restrict__ nin,
    const int* __restrict__ nout, const int* __restrict__ rel,
    const float* __restrict__ ew, int* __restrict__ cursor,
    int2* __restrict__ erec, int ne) {
  int e = blockIdx.x * 256 + threadIdx.x;
  if (e >= ne) return;
  int pos = atomicAdd(&cursor[(nout[e] << SEG_SHIFT) | rel[e]], 1);
  erec[pos] = make_int2(nin[e], __float_as_int(ew[e]));
}

// ---------- fused layer, relation-chunked ----------
// Per block: 16 dest nodes. For each rel r: half-wave aggregates its 2 nodes'
// edges into REGISTERS (no LDS RMW), dumps 16x128 tile to LDS, block multiplies
// tile @ W_r accumulating into per-thread output registers. Then self-loop,
// biases, relu, store.
__global__ __launch_bounds__(256) void layer_kernel(
    const float* __restrict__ x, const int2* __restrict__ erec,
    const int* __restrict__ row_ptr,
    const float* __restrict__ Wrel, const float* __restrict__ brel,
    const float* __restrict__ Wloop, const float* __restrict__ bloop,
    float* __restrict__ h, int n) {
  __shared__ float tile[MBLK][D];   // 16 x 128 fp32 = 8 KB
  const int t = threadIdx.x;
  const int m0 = blockIdx.x * MBLK;
  const float4* X4 = (const float4*)x;

  const int hw = t >> 5;         // half-wave id 0..7 (aggregation role)
  const int lane = t & 31;       // float4 lane within 128-float row
  const int na = m0 + hw * 2;    // this half-wave's two dest nodes
  const int nb_ = na + 1;

  const int tc = t & 31;         // transform: col group (4 cols as float4)
  const int tr = t >> 5;         // transform: row group
  const int ra = tr * 2, rb = ra + 1;
  const int ga = m0 + ra, gb = ga + 1;

  float4 acc0 = make_float4(0.f, 0.f, 0.f, 0.f);
  float4 acc1 = make_float4(0.f, 0.f, 0.f, 0.f);

  const float4* Wr4 = (const float4*)Wrel;   // (R*D) x 32 float4

  for (int r = 0; r < RNUM; ++r) {
    // --- aggregate this relation's edges into registers ---
    float4 agg0 = make_float4(0.f, 0.f, 0.f, 0.f);
    float4 agg1 = make_float4(0.f, 0.f, 0.f, 0.f);
    if (na < n) {
      const int seg = (na << SEG_SHIFT) | r;
      int s = row_ptr[seg], e = row_ptr[seg + 1];
      int j = s;
      for (; j + 1 < e; j += 2) {
        int2 r0 = erec[j];
        int2 r1 = erec[j + 1];
        float4 v0 = X4[(size_t)r0.x * 32 + lane];
        float4 v1 = X4[(size_t)r1.x * 32 + lane];
        float w0 = __int_as_float(r0.y);
        float w1 = __int_as_float(r1.y);
        agg0.x += w0 * v0.x; agg0.y += w0 * v0.y;
        agg0.z += w0 * v0.z; agg0.w += w0 * v0.w;
        agg0.x += w1 * v1.x; agg0.y += w1 * v1.y;
        agg0.z += w1 * v1.z; agg0.w += w1 * v1.w;
      }
      if (j < e) {
        int2 r0 = erec[j];
        float4 v0 = X4[(size_t)r0.x * 32 + lane];
        float w0 = __int_as_float(r0.y);
        agg0.x += w0 * v0.x; agg0.y += w0 * v0.y;
        agg0.z += w0 * v0.z; agg0.w += w0 * v0.w;
      }
    }
    if (nb_ < n) {
      const int seg = (nb_ << SEG_SHIFT) | r;
      int s = row_ptr[seg], e = row_ptr[seg + 1];
      int j = s;
      for (; j + 1 < e; j += 2) {
        int2 r0 = erec[j];
        int2 r1 = erec[j + 1];
        float4 v0 = X4[(size_t)r0.x * 32 + lane];
        float4 v1 = X4[(size_t)r1.x * 32 + lane];
        float w0 = __int_as_float(r0.y);
        float w1 = __int_as_float(r1.y);
        agg1.x += w0 * v0.x; agg1.y += w0 * v0.y;
        agg1.z += w0 * v0.z; agg1.w += w0 * v0.w;
        agg1.x += w1 * v1.x; agg1.y += w1 * v1.y;
        agg1.z += w1 * v1.z; agg1.w += w1 * v1.w;
      }
      if (j < e) {
        int2 r0 = erec[j];
        float4 v0 = X4[(size_t)r0.x * 32 + lane];
        float w0 = __int_as_float(r0.y);
        agg1.x += w0 * v0.x; agg1.y += w0 * v0.y;
        agg1.z += w0 * v0.z; agg1.w += w0 * v0.w;
      }
    }
    *(float4*)&tile[hw * 2 + 0][lane * 4] = agg0;
    *(float4*)&tile[hw * 2 + 1][lane * 4] = agg1;
    __syncthreads();

    // --- acc += tile @ W_r ---
    for (int k = 0; k < D; k += 4) {
      float4 a0 = *(const float4*)&tile[ra][k];
      float4 a1 = *(const float4*)&tile[rb][k];
#pragma unroll
      for (int kk = 0; kk < 4; ++kk) {
        float4 w = Wr4[(size_t)(r * D + k + kk) * 32 + tc];
        float e0 = (kk == 0) ? a0.x : (kk == 1) ? a0.y : (kk == 2) ? a0.z : a0.w;
        float e1 = (kk == 0) ? a1.x : (kk == 1) ? a1.y : (kk == 2) ? a1.z : a1.w;
        acc0.x += e0 * w.x; acc0.y += e0 * w.y; acc0.z += e0 * w.z; acc0.w += e0 * w.w;
        acc1.x += e1 * w.x; acc1.y += e1 * w.y; acc1.z += e1 * w.z; acc1.w += e1 * w.w;
      }
    }
    __syncthreads();   // before next rel overwrites tile
  }

  // --- self-loop term ---
  const float4* Wl4 = (const float4*)Wloop;   // 128 x 32 float4
  const bool ok0 = ga < n, ok1 = gb < n;
  for (int k = 0; k < D; k += 4) {
    float4 a0 = ok0 ? X4[(size_t)ga * 32 + (k >> 2)] : make_float4(0, 0, 0, 0);
    float4 a1 = ok1 ? X4[(size_t)gb * 32 + (k >> 2)] : make_float4(0, 0, 0, 0);
#pragma unroll
    for (int kk = 0; kk < 4; ++kk) {
      float4 w = Wl4[(size_t)(k + kk) * 32 + tc];
      float e0 = (kk == 0) ? a0.x : (kk == 1) ? a0.y : (kk == 2) ? a0.z : a0.w;
      float e1 = (kk == 0) ? a1.x : (kk == 1) ? a1.y : (kk == 2) ? a1.z : a1.w;
      acc0.x += e0 * w.x; acc0.y += e0 * w.y; acc0.z += e0 * w.z; acc0.w += e0 * w.w;
      acc1.x += e1 * w.x; acc1.y += e1 * w.y; acc1.z += e1 * w.z; acc1.w += e1 * w.w;
    }
  }

  float4 br = ((const float4*)brel)[tc];
  float4 bl = ((const float4*)bloop)[tc];
  float4 bias = make_float4(br.x + bl.x, br.y + bl.y, br.z + bl.z, br.w + bl.w);

  if (ok0) {
    float4 o;
    o.x = fmaxf(acc0.x + bias.x, 0.f); o.y = fmaxf(acc0.y + bias.y, 0.f);
    o.z = fmaxf(acc0.z + bias.z, 0.f); o.w = fmaxf(acc0.w + bias.w, 0.f);
    ((float4*)h)[(size_t)ga * 32 + tc] = o;
  }
  if (ok1) {
    float4 o;
    o.x = fmaxf(acc1.x + bias.x, 0.f); o.y = fmaxf(acc1.y + bias.y, 0.f);
    o.z = fmaxf(acc1.z + bias.z, 0.f); o.w = fmaxf(acc1.w + bias.w, 0.f);
    ((float4*)h)[(size_t)gb * 32 + tc] = o;
  }
}

// ---------- graph pooling (node2graph sorted) ----------
__global__ __launch_bounds__(256) void pool_kernel(const float* __restrict__ x,
    const int* __restrict__ n2g, float* __restrict__ gf, int n) {
  int d = threadIdx.x & 127;
  int sub = threadIdx.x >> 7;
  int n0 = (blockIdx.x * 2 + sub) * 128;
  int nend = n0 + 128;
  if (nend > n) nend = n;
  float acc = 0.f;
  int gcur = -1;
  for (int i = n0; i < nend; ++i) {
    int g = n2g[i];
    if (g != gcur) {
      if (gcur >= 0) atomicAdd(&gf[gcur * D + d], acc);
      gcur = g;
      acc = 0.f;
    }
    acc += x[(size_t)i * D + d];
  }
  if (gcur >= 0) atomicAdd(&gf[gcur * D + d], acc);
}

extern "C" void kernel_launch(void* const* d_in, const int* in_sizes, int n_in,
                              void* d_out, int out_size, void* d_ws, size_t ws_size,
                              hipStream_t stream) {
  const int*   unit_type  = (const int*)d_in[0];
  const int*   node_in    = (const int*)d_in[1];
  const int*   node_out   = (const int*)d_in[2];
  const int*   relation   = (const int*)d_in[3];
  const float* edge_w     = (const float*)d_in[4];
  const int*   node2graph = (const int*)d_in[5];
  const float* emb        = (const float*)d_in[6];
  const float* W_rel      = (const float*)d_in[7];
  const float* b_rel      = (const float*)d_in[8];
  const float* W_loop     = (const float*)d_in[9];
  const float* b_loop     = (const float*)d_in[10];

  const int n  = in_sizes[0];
  const int ne = in_sizes[1];
  float* out = (float*)d_out;

  const int nseg = n << SEG_SHIFT;
  const int nb   = (nseg + 1023) / 1024;

  // workspace layout
  const size_t ND = (size_t)n * D;
  float* x0       = (float*)d_ws;
  float* x1       = x0 + ND;
  int2*  erec     = (int2*)(x1 + ND);
  int*   hist     = (int*)(erec + ne);
  int*   row_ptr  = hist + nseg;
  int*   cursor   = row_ptr + ((nseg + 4) & ~3);
  int*   partials = cursor + nseg;

  hipMemsetAsync(d_out, 0, (size_t)GNUM * D * sizeof(float), stream);
  hipMemsetAsync(hist, 0, (size_t)nseg * sizeof(int), stream);

  const int eblocks = (ne + 255) / 256;
  hist_kernel<<<eblocks, 256, 0, stream>>>(node_out, relation, hist, ne);
  scan1_kernel<<<nb, 256, 0, stream>>>(hist, row_ptr, partials, nseg);
  scan2_kernel<<<1, 256, 0, stream>>>(partials, nb);
  scan3_kernel<<<(nseg + 255) / 256, 256, 0, stream>>>(row_ptr, cursor, partials, nseg, ne);
  fill_kernel<<<eblocks, 256, 0, stream>>>(node_in, node_out, relation, edge_w,
                                           cursor, erec, ne);

  const int nq = n * 32;
  init_x_kernel<<<(nq + 255) / 256, 256, 0, stream>>>(unit_type, emb, x0, n);

  const int lblocks = (n + MBLK - 1) / MBLK;
  float* cur = x0;
  for (int i = 0; i < LAYERS; ++i) {
    float* nxt = (i == LAYERS - 1) ? (out + GNUM * D) : (cur == x0 ? x1 : x0);
    layer_kernel<<<lblocks, 256, 0, stream>>>(
        cur, erec, row_ptr,
        W_rel + (size_t)i * RNUM * D * D, b_rel + (size_t)i * D,
        W_loop + (size_t)i * D * D, b_loop + (size_t)i * D,
        nxt, n);
    cur = nxt;
  }

  pool_kernel<<<(n + 255) / 256, 256, 0, stream>>>(cur, node2graph, out, n);
}